// Round 1
// baseline (427.404 us; speedup 1.0000x reference)
//
#include <hip/hip_runtime.h>
#include <hip/hip_bf16.h>

#define UHG_EPS 1e-9
#define ZDIM 128

// ---------------- device helpers ----------------

__device__ __forceinline__ double safe_den(double den) {
    // jnp: maximum(|den|, EPS) * sign(den). sign(0)=0 has prob 0; copysign ok.
    return copysign(fmax(fabs(den), UHG_EPS), den);
}

template <int STRIDE>
__device__ __forceinline__ double quad_pair(const float* __restrict__ xy, int s, int d) {
    float xaf = xy[(size_t)s * STRIDE];
    float yaf = xy[(size_t)s * STRIDE + 1];
    float xbf = xy[(size_t)d * STRIDE];
    float ybf = xy[(size_t)d * STRIDE + 1];
    double xa = xaf, ya = yaf, xb = xbf, yb = ybf;
    double aa = 1.0 - (xa * xa + ya * ya);
    double bb = 1.0 - (xb * xb + yb * yb);
    double ab = 1.0 - (xa * xb + ya * yb);
    double den = aa * bb;
    double num = ab * ab - den;
    return num / safe_den(den);
}

__device__ __forceinline__ void wave_reduce_atomic(double local, double* dst) {
    local += __shfl_down(local, 32);
    local += __shfl_down(local, 16);
    local += __shfl_down(local, 8);
    local += __shfl_down(local, 4);
    local += __shfl_down(local, 2);
    local += __shfl_down(local, 1);
    if ((threadIdx.x & 63) == 0) atomicAdd(dst, local);
}

// ---------------- kernels ----------------

// Build (x,y) table (optional) + compactness sum: quad(node, origin) = (1-aa)/safe(aa)
__global__ void node_kernel(const float* __restrict__ z, float* __restrict__ table,
                            double* __restrict__ comp_sum, int N) {
    int i = blockIdx.x * blockDim.x + threadIdx.x;
    double local = 0.0;
    if (i < N) {
        const float2* zp = (const float2*)z;           // row i starts at float2 index i*64
        float2 v = zp[(size_t)i * (ZDIM / 2)];
        if (table) {
            float2* t = (float2*)table;
            t[i] = v;
        }
        double x = v.x, y = v.y;
        double aa = 1.0 - (x * x + y * y);
        double num = 1.0 - aa;                         // ab^2 - aa*bb with ab=1, bb=1
        local = num / safe_den(aa);
    }
    wave_reduce_atomic(local, comp_sum);
}

// Proximity sum over all edges. STRIDE=2 -> compact table; STRIDE=ZDIM -> direct from z.
template <int STRIDE>
__global__ void edge_kernel(const int4* __restrict__ src4, const int4* __restrict__ dst4, int nvec,
                            const int* __restrict__ src, const int* __restrict__ dst, int E,
                            const float* __restrict__ xy, double* __restrict__ prox_sum) {
    double local = 0.0;
    int tid = blockIdx.x * blockDim.x + threadIdx.x;
    int stride = gridDim.x * blockDim.x;
    for (int v = tid; v < nvec; v += stride) {
        int4 s = src4[v];
        int4 d = dst4[v];
        local += quad_pair<STRIDE>(xy, s.x, d.x);
        local += quad_pair<STRIDE>(xy, s.y, d.y);
        local += quad_pair<STRIDE>(xy, s.z, d.z);
        local += quad_pair<STRIDE>(xy, s.w, d.w);
    }
    for (int e = 4 * nvec + tid; e < E; e += stride) {
        local += quad_pair<STRIDE>(xy, src[e], dst[e]);
    }
    wave_reduce_atomic(local, prox_sum);
}

// Spread over first min(10,E) edges + final combine. Single thread (10 edges is noise).
__global__ void finalize_kernel(const int* __restrict__ src, const int* __restrict__ dst,
                                const float* __restrict__ z, const double* __restrict__ sums,
                                float* __restrict__ out, int N, int E) {
    if (blockIdx.x != 0 || threadIdx.x != 0) return;
    double prox = sums[0] / (double)E;
    double comp = sums[1] / (double)N;
    int n_sp = E < 10 ? E : 10;
    double spread = 0.0;
    for (int k = 0; k < n_sp; k++) {
        int s = src[k], d = dst[k];
        double xa = z[(size_t)s * ZDIM], ya = z[(size_t)s * ZDIM + 1];
        double xb = z[(size_t)d * ZDIM], yb = z[(size_t)d * ZDIM + 1];
        // lines: (y, -x, 0); uhg_inner(la,lb) = -(ya*yb + xa*xb) + 0
        double aa = -(ya * ya + xa * xa);
        double bb = -(yb * yb + xb * xb);
        double ab = -(ya * yb + xa * xb);
        double den = aa * bb;
        double num = ab * ab - den;
        spread += num / safe_den(den);
    }
    if (n_sp > 0) spread /= (double)n_sp;
    out[0] = (float)(1.0 * (prox + comp) + 0.1 * spread);
}

// ---------------- launch ----------------

extern "C" void kernel_launch(void* const* d_in, const int* in_sizes, int n_in,
                              void* d_out, int out_size, void* d_ws, size_t ws_size,
                              hipStream_t stream) {
    const float* z = (const float*)d_in[0];
    const int* edge_index = (const int*)d_in[1];
    float* out = (float*)d_out;

    const int N = in_sizes[0] / ZDIM;
    const int E = in_sizes[1] / 2;
    const int* src = edge_index;
    const int* dst = edge_index + (size_t)E;

    // ws layout: [0..16) two double accumulators (prox, comp); [256..) float2 table
    double* sums = (double*)d_ws;
    float* table = (float*)((char*)d_ws + 256);
    bool use_table = ws_size >= 256 + (size_t)N * 2 * sizeof(float);

    hipMemsetAsync(d_ws, 0, 256, stream);

    {
        int blocks = (N + 255) / 256;
        node_kernel<<<blocks, 256, 0, stream>>>(z, use_table ? table : nullptr, sums + 1, N);
    }

    {
        int nvec = E / 4;
        const int4* src4 = (const int4*)src;
        const int4* dst4 = (const int4*)dst;
        int blocks = (nvec + 255) / 256;
        if (blocks > 4096) blocks = 4096;
        if (blocks < 1) blocks = 1;
        if (use_table) {
            edge_kernel<2><<<blocks, 256, 0, stream>>>(src4, dst4, nvec, src, dst, E, table, sums);
        } else {
            edge_kernel<ZDIM><<<blocks, 256, 0, stream>>>(src4, dst4, nvec, src, dst, E, z, sums);
        }
    }

    finalize_kernel<<<1, 64, 0, stream>>>(src, dst, z, sums, out, N, E);
}

// Round 2
// 295.205 us; speedup vs baseline: 1.4478x; 1.4478x over previous
//
#include <hip/hip_runtime.h>
#include <hip/hip_bf16.h>

#define UHG_EPS 1e-9
#define ZDIM 128

#define EDGE_BLOCKS 2048
#define NODE_BLOCKS 1024
#define BLOCK 256

// ws layout:
//   [0            , 16 KB)  : 2048 double prox partials (one per edge block)
//   [16 KB        , 24 KB)  : 1024 double comp partials (one per node block)
//   [24 KB        , ...  )  : float2 table[N] (compact x,y per node)
#define PROX_OFF 0
#define COMP_OFF (16 * 1024)
#define TABLE_OFF (24 * 1024)

// ---------------- device helpers ----------------

__device__ __forceinline__ double safe_den(double den) {
    return copysign(fmax(fabs(den), UHG_EPS), den);
}

__device__ __forceinline__ double quad_xy(float2 a, float2 b) {
    double xa = a.x, ya = a.y, xb = b.x, yb = b.y;
    double aa = 1.0 - (xa * xa + ya * ya);
    double bb = 1.0 - (xb * xb + yb * yb);
    double ab = 1.0 - (xa * xb + ya * yb);
    double den = aa * bb;
    double num = ab * ab - den;
    return num / safe_den(den);
}

// Block reduction: returns total on thread 0. sh must hold >= 8 doubles.
__device__ __forceinline__ double block_reduce(double v, double* sh) {
    int lane = threadIdx.x & 63;
    int wid = threadIdx.x >> 6;
    v += __shfl_down(v, 32);
    v += __shfl_down(v, 16);
    v += __shfl_down(v, 8);
    v += __shfl_down(v, 4);
    v += __shfl_down(v, 2);
    v += __shfl_down(v, 1);
    if (lane == 0) sh[wid] = v;
    __syncthreads();
    double r = 0.0;
    if (wid == 0) {
        int nw = blockDim.x >> 6;
        r = (lane < nw) ? sh[lane] : 0.0;
        r += __shfl_down(r, 4);
        r += __shfl_down(r, 2);
        r += __shfl_down(r, 1);
    }
    __syncthreads();
    return r;
}

// ---------------- kernels ----------------

// Build compact (x,y) table + compactness partials. Grid = NODE_BLOCKS fixed.
__global__ __launch_bounds__(BLOCK) void node_kernel(const float* __restrict__ z,
                                                     float2* __restrict__ table,
                                                     double* __restrict__ comp_partials, int N) {
    __shared__ double sh[8];
    const float2* zp = (const float2*)z;
    double local = 0.0;
    for (int i = blockIdx.x * BLOCK + threadIdx.x; i < N; i += NODE_BLOCKS * BLOCK) {
        float2 v = zp[(size_t)i * (ZDIM / 2)];
        if (table) table[i] = v;
        double x = v.x, y = v.y;
        double aa = 1.0 - (x * x + y * y);
        local += (1.0 - aa) / safe_den(aa);   // ab=1, bb=1 against origin
    }
    double tot = block_reduce(local, sh);
    if (threadIdx.x == 0) comp_partials[blockIdx.x] = tot;
}

// Proximity partials over all edges. Grid = EDGE_BLOCKS fixed.
// STRIDE2 = 1 -> compact table (float2 index = node id); 0 -> direct from z (index = id*64).
template <int COMPACT>
__global__ __launch_bounds__(BLOCK) void edge_kernel(const int4* __restrict__ src4,
                                                     const int4* __restrict__ dst4, int nvec,
                                                     const int* __restrict__ src,
                                                     const int* __restrict__ dst, int E,
                                                     const float2* __restrict__ xy,
                                                     double* __restrict__ prox_partials) {
    __shared__ double sh[8];
    double local = 0.0;
    int tid = blockIdx.x * BLOCK + threadIdx.x;
    const int gstride = EDGE_BLOCKS * BLOCK;
    const size_t mul = COMPACT ? 1 : (ZDIM / 2);
    for (int v = tid; v < nvec; v += gstride) {
        int4 s = src4[v];
        int4 d = dst4[v];
        float2 a0 = xy[(size_t)s.x * mul], b0 = xy[(size_t)d.x * mul];
        float2 a1 = xy[(size_t)s.y * mul], b1 = xy[(size_t)d.y * mul];
        float2 a2 = xy[(size_t)s.z * mul], b2 = xy[(size_t)d.z * mul];
        float2 a3 = xy[(size_t)s.w * mul], b3 = xy[(size_t)d.w * mul];
        local += quad_xy(a0, b0);
        local += quad_xy(a1, b1);
        local += quad_xy(a2, b2);
        local += quad_xy(a3, b3);
    }
    for (int e = 4 * nvec + tid; e < E; e += gstride) {
        local += quad_xy(xy[(size_t)src[e] * mul], xy[(size_t)dst[e] * mul]);
    }
    double tot = block_reduce(local, sh);
    if (threadIdx.x == 0) prox_partials[blockIdx.x] = tot;
}

// Sum partials + spread over first min(10,E) edges + combine. One block of 256.
__global__ __launch_bounds__(BLOCK) void finalize_kernel(const int* __restrict__ src,
                                                         const int* __restrict__ dst,
                                                         const float* __restrict__ z,
                                                         const double* __restrict__ prox_partials,
                                                         const double* __restrict__ comp_partials,
                                                         float* __restrict__ out, int N, int E) {
    __shared__ double sh[8];
    int t = threadIdx.x;

    double pl = 0.0;
    for (int i = t; i < EDGE_BLOCKS; i += BLOCK) pl += prox_partials[i];
    double prox = block_reduce(pl, sh);

    double cl = 0.0;
    for (int i = t; i < NODE_BLOCKS; i += BLOCK) cl += comp_partials[i];
    double comp = block_reduce(cl, sh);

    int n_sp = E < 10 ? E : 10;
    double sl = 0.0;
    if (t < n_sp) {
        int s = src[t], d = dst[t];
        double xa = z[(size_t)s * ZDIM], ya = z[(size_t)s * ZDIM + 1];
        double xb = z[(size_t)d * ZDIM], yb = z[(size_t)d * ZDIM + 1];
        // lines = cross(point, origin[0,0,1]) = (y, -x, 0)
        // uhg_inner(la,lb) = -(la_x*lb_x + la_y*lb_y) + 0
        double aa = -(ya * ya + xa * xa);
        double bb = -(yb * yb + xb * xb);
        double ab = -(ya * yb + xa * xb);
        double den = aa * bb;
        sl = (ab * ab - den) / safe_den(den);
    }
    double spread = block_reduce(sl, sh);

    if (t == 0) {
        double loss = prox / (double)E + comp / (double)N;
        if (n_sp > 0) loss += 0.1 * (spread / (double)n_sp);
        out[0] = (float)loss;
    }
}

// ---------------- launch ----------------

extern "C" void kernel_launch(void* const* d_in, const int* in_sizes, int n_in,
                              void* d_out, int out_size, void* d_ws, size_t ws_size,
                              hipStream_t stream) {
    const float* z = (const float*)d_in[0];
    const int* edge_index = (const int*)d_in[1];
    float* out = (float*)d_out;

    const int N = in_sizes[0] / ZDIM;
    const int E = in_sizes[1] / 2;
    const int* src = edge_index;
    const int* dst = edge_index + (size_t)E;

    double* prox_partials = (double*)((char*)d_ws + PROX_OFF);
    double* comp_partials = (double*)((char*)d_ws + COMP_OFF);
    float2* table = (float2*)((char*)d_ws + TABLE_OFF);
    bool use_table = ws_size >= TABLE_OFF + (size_t)N * sizeof(float2);

    node_kernel<<<NODE_BLOCKS, BLOCK, 0, stream>>>(z, use_table ? table : nullptr,
                                                   comp_partials, N);

    int nvec = E / 4;
    const int4* src4 = (const int4*)src;
    const int4* dst4 = (const int4*)dst;
    if (use_table) {
        edge_kernel<1><<<EDGE_BLOCKS, BLOCK, 0, stream>>>(src4, dst4, nvec, src, dst, E,
                                                          table, prox_partials);
    } else {
        edge_kernel<0><<<EDGE_BLOCKS, BLOCK, 0, stream>>>(src4, dst4, nvec, src, dst, E,
                                                          (const float2*)z, prox_partials);
    }

    finalize_kernel<<<1, BLOCK, 0, stream>>>(src, dst, z, prox_partials, comp_partials,
                                             out, N, E);
}